// Round 6
// baseline (268.103 us; speedup 1.0000x reference)
//
#include <hip/hip_runtime.h>
#include <cfloat>
#include <math.h>

#define N_OBJ 8
#define N_PTS 2048
#define KNN   10
#define TOLC  0.01f
#define TPB   256
#define PPB   64                 // p's per block (one per lane)
#define QCH   4                  // q-chunks = waves per block
#define QLEN  (N_PTS / QCH)      // 512 q's per wave
#define PTILES (N_PTS / PPB)     // 32 p-tiles per pair

typedef float f32x2 __attribute__((ext_vector_type(2)));

// ---- order-preserving float <-> uint for atomicMin on signed floats ----
__device__ __forceinline__ unsigned int enc_f(float f) {
    unsigned int u = __float_as_uint(f);
    return (u & 0x80000000u) ? ~u : (u | 0x80000000u);
}
__device__ __forceinline__ float dec_f(unsigned int e) {
    unsigned int u = (e & 0x80000000u) ? (e & 0x7fffffffu) : ~e;
    return __uint_as_float(u);
}

// Kernel 1: per-point transform (4x4 inverse redundantly in double — closer
// to the numpy reference than fp32 adjugate; trivial at this grid size).
// Writes interleaved record Q8[q] = (x,nx, y,ny, z,nz, sq,w) with
// sq=|x|^2, w=dot(n,x) — pairs aligned for v_pk_fma_f32 in k_pairs.
__global__ void k_transform(const float* __restrict__ pts,
                            const float* __restrict__ T_est,
                            const float* __restrict__ T_plane,
                            float4* __restrict__ Q8,
                            unsigned int* __restrict__ SD) {
    int gid = blockIdx.x * blockDim.x + threadIdx.x;
    if (gid >= N_OBJ * N_PTS) return;
    int b = gid >> 11;

    double m[16];
#pragma unroll
    for (int i = 0; i < 16; i++) m[i] = (double)T_plane[i];
    double inv[16];
    inv[0]  =  m[5]*m[10]*m[15] - m[5]*m[11]*m[14] - m[9]*m[6]*m[15] + m[9]*m[7]*m[14] + m[13]*m[6]*m[11] - m[13]*m[7]*m[10];
    inv[4]  = -m[4]*m[10]*m[15] + m[4]*m[11]*m[14] + m[8]*m[6]*m[15] - m[8]*m[7]*m[14] - m[12]*m[6]*m[11] + m[12]*m[7]*m[10];
    inv[8]  =  m[4]*m[9]*m[15]  - m[4]*m[11]*m[13] - m[8]*m[5]*m[15] + m[8]*m[7]*m[13] + m[12]*m[5]*m[11] - m[12]*m[7]*m[9];
    inv[12] = -m[4]*m[9]*m[14]  + m[4]*m[10]*m[13] + m[8]*m[5]*m[14] - m[8]*m[6]*m[13] - m[12]*m[5]*m[10] + m[12]*m[6]*m[9];
    inv[1]  = -m[1]*m[10]*m[15] + m[1]*m[11]*m[14] + m[9]*m[2]*m[15] - m[9]*m[3]*m[14] - m[13]*m[2]*m[11] + m[13]*m[3]*m[10];
    inv[5]  =  m[0]*m[10]*m[15] - m[0]*m[11]*m[14] - m[8]*m[2]*m[15] + m[8]*m[3]*m[14] + m[12]*m[2]*m[11] - m[12]*m[3]*m[10];
    inv[9]  = -m[0]*m[9]*m[15]  + m[0]*m[11]*m[13] + m[8]*m[1]*m[15] - m[8]*m[3]*m[13] - m[12]*m[1]*m[11] + m[12]*m[3]*m[9];
    inv[13] =  m[0]*m[9]*m[14]  - m[0]*m[10]*m[13] - m[8]*m[1]*m[14] + m[8]*m[2]*m[13] + m[12]*m[1]*m[10] - m[12]*m[2]*m[9];
    inv[2]  =  m[1]*m[6]*m[15]  - m[1]*m[7]*m[14]  - m[5]*m[2]*m[15] + m[5]*m[3]*m[14] + m[13]*m[2]*m[7]  - m[13]*m[3]*m[6];
    inv[6]  = -m[0]*m[6]*m[15]  + m[0]*m[7]*m[14]  + m[4]*m[2]*m[15] - m[4]*m[3]*m[14] - m[12]*m[2]*m[7]  + m[12]*m[3]*m[6];
    inv[10] =  m[0]*m[5]*m[15]  - m[0]*m[7]*m[13]  - m[4]*m[1]*m[15] + m[4]*m[3]*m[13] + m[12]*m[1]*m[7]  - m[12]*m[3]*m[5];
    inv[14] = -m[0]*m[5]*m[14]  + m[0]*m[6]*m[13]  + m[4]*m[1]*m[14] - m[4]*m[2]*m[13] - m[12]*m[1]*m[6]  + m[12]*m[2]*m[5];
    inv[3]  = -m[1]*m[6]*m[11]  + m[1]*m[7]*m[10]  + m[5]*m[2]*m[11] - m[5]*m[3]*m[10] - m[9]*m[2]*m[7]   + m[9]*m[3]*m[6];
    inv[7]  =  m[0]*m[6]*m[11]  - m[0]*m[7]*m[10]  - m[4]*m[2]*m[11] + m[4]*m[3]*m[10] + m[8]*m[2]*m[7]   - m[8]*m[3]*m[6];
    inv[11] = -m[0]*m[5]*m[11]  + m[0]*m[7]*m[9]   + m[4]*m[1]*m[11] - m[4]*m[3]*m[9]  - m[8]*m[1]*m[7]   + m[8]*m[3]*m[5];
    inv[15] =  m[0]*m[5]*m[10]  - m[0]*m[6]*m[9]   - m[4]*m[1]*m[10] + m[4]*m[2]*m[9]  + m[8]*m[1]*m[6]   - m[8]*m[2]*m[5];
    double det  = m[0]*inv[0] + m[1]*inv[4] + m[2]*inv[8] + m[3]*inv[12];
    double rdet = 1.0 / det;

    const float* Te = T_est + b * 16;
    double M[12];
#pragma unroll
    for (int i = 0; i < 3; i++)
#pragma unroll
        for (int j = 0; j < 4; j++) {
            double s = 0.0;
#pragma unroll
            for (int kk = 0; kk < 4; kk++) s += inv[i*4+kk] * rdet * (double)Te[kk*4+j];
            M[i*4+j] = s;
        }

    const float* pp = pts + (size_t)gid * 6;
    double px = pp[0], py = pp[1], pz = pp[2];
    float nx = pp[3], ny = pp[4], nz = pp[5];
    float x = (float)(M[0]*px + M[1]*py + M[2]*pz  + M[3]);
    float y = (float)(M[4]*px + M[5]*py + M[6]*pz  + M[7]);
    float z = (float)(M[8]*px + M[9]*py + M[10]*pz + M[11]);
    float sq = fmaf(x, x, fmaf(y, y, z * z));
    float w  = fmaf(nx, x, fmaf(ny, y, nz * z));
    Q8[(size_t)gid * 2]     = make_float4(x, nx, y, ny);
    Q8[(size_t)gid * 2 + 1] = make_float4(z, nz, sq, w);
    SD[gid] = enc_f(z);   // seed min with the plane-distance term z
}

// Kernel 2: grid = 56 pairs x 32 p-tiles = 1792 blocks (7/CU), 256 threads.
// Lane = p (64 p's/block); wave w scans q-chunk w (512 q's) of object o.
// CRITICAL: the q-stream address is offset by an mbcnt-derived zero the
// compiler must treat as divergent. Without it (R4/R5) the wave-uniform
// loads scalarize to s_load/SMEM: VGPR_Count collapsed to 20, SMEM's
// out-of-order completion forces lgkmcnt(0) full drains, and the loop ran
// latency-serialized at 152 cyc/iter (227us). With it (R3) loads stay
// global_load_dwordx4 on vmcnt with fine-grained waits.
// Body: (c,s) via 3 v_pk_fma_f32, inside-sign packed in c's mantissa LSB,
// 10-deep med3 insertion (index-free). Epilogue: partial top-10s -> LDS,
// wave 0 merges 4 lists element-wise (exact), counts LSBs, atomicMin.
__global__ void __launch_bounds__(TPB) k_pairs(const float4* __restrict__ Q8,
                                               unsigned int* __restrict__ SD) {
    __shared__ float TD[TPB][KNN + 1];   // 11 KiB, padded
    int bx   = blockIdx.x;
    int pair = bx >> 5;                  // / PTILES
    int tile = bx & (PTILES - 1);
    int b  = pair / 7;
    int oi = pair % 7;
    int o  = oi + (oi >= b ? 1 : 0);
    int tid  = threadIdx.x;
    int lane = tid & 63;
    int wave = tid >> 6;

    int p = tile * PPB + lane;
    const float4* Qp = Q8 + ((size_t)b * N_PTS + p) * 2;
    float4 u = Qp[0];                    // (x, nx, y, ny)
    float4 v = Qp[1];                    // (z, nz, sq, w)
    float px = u.x, py = u.z, pz = v.x, sqp = v.z;
    f32x2 B1 = {-2.0f * px, -px};
    f32x2 B2 = {-2.0f * py, -py};
    f32x2 B3 = {-2.0f * pz, -pz};

    // divergent-looking zero: keeps the q-stream on the VMEM path (see above)
    int dz0 = (int)__builtin_amdgcn_mbcnt_lo(0u, 0u);
    const float4* Qo = Q8 + ((size_t)o * N_PTS + wave * QLEN + dz0) * 2;

    const float FMAXE = __uint_as_float(0x7F7FFFFEu);   // FLT_MAX, LSB clear
    float td[KNN];
#pragma unroll
    for (int j = 0; j < KNN; j++) td[j] = FMAXE;

#pragma unroll 4
    for (int q = 0; q < QLEN; q++) {
        float4 a0 = Qo[2 * q];           // (x, nx, y, ny)
        float4 a1 = Qo[2 * q + 1];       // (z, nz, sq, w)
        f32x2 A1 = {a0.x, a0.y};
        f32x2 A2 = {a0.z, a0.w};
        f32x2 A3 = {a1.x, a1.y};
        f32x2 C0 = {a1.z, a1.w};
        f32x2 r = __builtin_elementwise_fma(A1, B1,
                  __builtin_elementwise_fma(A2, B2,
                  __builtin_elementwise_fma(A3, B3, C0)));
        // r.x = sq_q - 2 dot(xq,xp)  (d2 minus constant sq_p)
        // r.y = dot(n_q, xq - xp)    (inside sign)
        unsigned int cu = (__float_as_uint(r.x) & 0xFFFFFFFEu) | (r.y > 0.0f ? 1u : 0u);
        float cp = __uint_as_float(cu);
#pragma unroll
        for (int j = KNN - 1; j >= 1; --j)
            td[j] = __builtin_amdgcn_fmed3f(td[j - 1], td[j], cp);
        td[0] = fminf(td[0], cp);
    }

#pragma unroll
    for (int j = 0; j < KNN; j++) TD[tid][j] = td[j];
    __syncthreads();

    if (tid < PPB) {
#pragma unroll
        for (int c = 1; c < QCH; c++) {
#pragma unroll
            for (int j = 0; j < KNN; j++) {
                float cp = TD[c * PPB + tid][j];
#pragma unroll
                for (int jj = KNN - 1; jj >= 1; --jj)
                    td[jj] = __builtin_amdgcn_fmed3f(td[jj - 1], td[jj], cp);
                td[0] = fminf(td[0], cp);
            }
        }
        int cnt = 0;
#pragma unroll
        for (int j = 0; j < KNN; j++) cnt += (int)(__float_as_uint(td[j]) & 1u);
        float d2 = __uint_as_float(__float_as_uint(td[0]) & 0xFFFFFFFEu) + sqp;
        float d0 = sqrtf(fmaxf(d2, 0.0f));
        if (cnt > 8) d0 = -d0;           // sum(insides) > k*0.8 = 8  ->  >= 9
        atomicMin(&SD[b * N_PTS + p], enc_f(d0));
    }
}

// Kernel 3: decode and emit both outputs (signed_distance, then intersects
// as 0.0/1.0 floats).
__global__ void k_final(const unsigned int* __restrict__ SD,
                        float* __restrict__ out) {
    int gid = blockIdx.x * blockDim.x + threadIdx.x;
    if (gid >= N_OBJ * N_PTS) return;
    float sd = dec_f(SD[gid]);
    out[gid] = sd;
    out[N_OBJ * N_PTS + gid] = (sd < -TOLC) ? 1.0f : 0.0f;
}

extern "C" void kernel_launch(void* const* d_in, const int* in_sizes, int n_in,
                              void* d_out, int out_size, void* d_ws, size_t ws_size,
                              hipStream_t stream) {
    const float* pts     = (const float*)d_in[0];   // (8,2048,6)
    const float* T_est   = (const float*)d_in[1];   // (8,4,4)
    const float* T_plane = (const float*)d_in[2];   // (4,4)
    // d_in[3] is k == 10, hardcoded as KNN

    // workspace layout: Q8 (512KB interleaved records) | SD (64KB)
    float4*       Q8 = (float4*)d_ws;
    unsigned int* SD = (unsigned int*)(Q8 + (size_t)N_OBJ * N_PTS * 2);

    float* out = (float*)d_out;

    k_transform<<<(N_OBJ * N_PTS) / 256, 256, 0, stream>>>(pts, T_est, T_plane, Q8, SD);
    k_pairs<<<N_OBJ * (N_OBJ - 1) * PTILES, TPB, 0, stream>>>(Q8, SD);
    k_final<<<(N_OBJ * N_PTS) / 256, 256, 0, stream>>>(SD, out);
}

// Round 7
// 213.018 us; speedup vs baseline: 1.2586x; 1.2586x over previous
//
#include <hip/hip_runtime.h>
#include <cfloat>
#include <math.h>

#define N_OBJ 8
#define N_PTS 2048
#define KNN   10
#define TOLC  0.01f
#define TPB   256
#define RPL   4                  // p-slots per lane (register tiling)
#define PCOV  (64 * RPL)         // 256 p's covered per block
#define QCH   4                  // q-chunks = waves per block
#define QLEN  (N_PTS / QCH)      // 512 q's per wave
#define PTILES (N_PTS / PCOV)    // 8 p-tiles per pair

typedef float f32x2 __attribute__((ext_vector_type(2)));

// ---- order-preserving float <-> uint for atomicMin on signed floats ----
__device__ __forceinline__ unsigned int enc_f(float f) {
    unsigned int u = __float_as_uint(f);
    return (u & 0x80000000u) ? ~u : (u | 0x80000000u);
}
__device__ __forceinline__ float dec_f(unsigned int e) {
    unsigned int u = (e & 0x80000000u) ? (e & 0x7fffffffu) : ~e;
    return __uint_as_float(u);
}

// Kernel 1: per-point transform (4x4 inverse redundantly in double — closer
// to the numpy reference than fp32 adjugate; trivial at this grid size).
// Writes interleaved record Q8[q] = (x,nx, y,ny, z,nz, sq,w) with
// sq=|x|^2, w=dot(n,x) — pairs aligned for v_pk_fma_f32 in k_pairs.
__global__ void k_transform(const float* __restrict__ pts,
                            const float* __restrict__ T_est,
                            const float* __restrict__ T_plane,
                            float4* __restrict__ Q8,
                            unsigned int* __restrict__ SD) {
    int gid = blockIdx.x * blockDim.x + threadIdx.x;
    if (gid >= N_OBJ * N_PTS) return;
    int b = gid >> 11;

    double m[16];
#pragma unroll
    for (int i = 0; i < 16; i++) m[i] = (double)T_plane[i];
    double inv[16];
    inv[0]  =  m[5]*m[10]*m[15] - m[5]*m[11]*m[14] - m[9]*m[6]*m[15] + m[9]*m[7]*m[14] + m[13]*m[6]*m[11] - m[13]*m[7]*m[10];
    inv[4]  = -m[4]*m[10]*m[15] + m[4]*m[11]*m[14] + m[8]*m[6]*m[15] - m[8]*m[7]*m[14] - m[12]*m[6]*m[11] + m[12]*m[7]*m[10];
    inv[8]  =  m[4]*m[9]*m[15]  - m[4]*m[11]*m[13] - m[8]*m[5]*m[15] + m[8]*m[7]*m[13] + m[12]*m[5]*m[11] - m[12]*m[7]*m[9];
    inv[12] = -m[4]*m[9]*m[14]  + m[4]*m[10]*m[13] + m[8]*m[5]*m[14] - m[8]*m[6]*m[13] - m[12]*m[5]*m[10] + m[12]*m[6]*m[9];
    inv[1]  = -m[1]*m[10]*m[15] + m[1]*m[11]*m[14] + m[9]*m[2]*m[15] - m[9]*m[3]*m[14] - m[13]*m[2]*m[11] + m[13]*m[3]*m[10];
    inv[5]  =  m[0]*m[10]*m[15] - m[0]*m[11]*m[14] - m[8]*m[2]*m[15] + m[8]*m[3]*m[14] + m[12]*m[2]*m[11] - m[12]*m[3]*m[10];
    inv[9]  = -m[0]*m[9]*m[15]  + m[0]*m[11]*m[13] + m[8]*m[1]*m[15] - m[8]*m[3]*m[13] - m[12]*m[1]*m[11] + m[12]*m[3]*m[9];
    inv[13] =  m[0]*m[9]*m[14]  - m[0]*m[10]*m[13] - m[8]*m[1]*m[14] + m[8]*m[2]*m[13] + m[12]*m[1]*m[10] - m[12]*m[2]*m[9];
    inv[2]  =  m[1]*m[6]*m[15]  - m[1]*m[7]*m[14]  - m[5]*m[2]*m[15] + m[5]*m[3]*m[14] + m[13]*m[2]*m[7]  - m[13]*m[3]*m[6];
    inv[6]  = -m[0]*m[6]*m[15]  + m[0]*m[7]*m[14]  + m[4]*m[2]*m[15] - m[4]*m[3]*m[14] - m[12]*m[2]*m[7]  + m[12]*m[3]*m[6];
    inv[10] =  m[0]*m[5]*m[15]  - m[0]*m[7]*m[13]  - m[4]*m[1]*m[15] + m[4]*m[3]*m[13] + m[12]*m[1]*m[7]  - m[12]*m[3]*m[5];
    inv[14] = -m[0]*m[5]*m[14]  + m[0]*m[6]*m[13]  + m[4]*m[1]*m[14] - m[4]*m[2]*m[13] - m[12]*m[1]*m[6]  + m[12]*m[2]*m[5];
    inv[3]  = -m[1]*m[6]*m[11]  + m[1]*m[7]*m[10]  + m[5]*m[2]*m[11] - m[5]*m[3]*m[10] - m[9]*m[2]*m[7]   + m[9]*m[3]*m[6];
    inv[7]  =  m[0]*m[6]*m[11]  - m[0]*m[7]*m[10]  - m[4]*m[2]*m[11] + m[4]*m[3]*m[10] + m[8]*m[2]*m[7]   - m[8]*m[3]*m[6];
    inv[11] = -m[0]*m[5]*m[11]  + m[0]*m[7]*m[9]   + m[4]*m[1]*m[11] - m[4]*m[3]*m[9]  - m[8]*m[1]*m[7]   + m[8]*m[3]*m[5];
    inv[15] =  m[0]*m[5]*m[10]  - m[0]*m[6]*m[9]   - m[4]*m[1]*m[10] + m[4]*m[2]*m[9]  + m[8]*m[1]*m[6]   - m[8]*m[2]*m[5];
    double det  = m[0]*inv[0] + m[1]*inv[4] + m[2]*inv[8] + m[3]*inv[12];
    double rdet = 1.0 / det;

    const float* Te = T_est + b * 16;
    double M[12];
#pragma unroll
    for (int i = 0; i < 3; i++)
#pragma unroll
        for (int j = 0; j < 4; j++) {
            double s = 0.0;
#pragma unroll
            for (int kk = 0; kk < 4; kk++) s += inv[i*4+kk] * rdet * (double)Te[kk*4+j];
            M[i*4+j] = s;
        }

    const float* pp = pts + (size_t)gid * 6;
    double px = pp[0], py = pp[1], pz = pp[2];
    float nx = pp[3], ny = pp[4], nz = pp[5];
    float x = (float)(M[0]*px + M[1]*py + M[2]*pz  + M[3]);
    float y = (float)(M[4]*px + M[5]*py + M[6]*pz  + M[7]);
    float z = (float)(M[8]*px + M[9]*py + M[10]*pz + M[11]);
    float sq = fmaf(x, x, fmaf(y, y, z * z));
    float w  = fmaf(nx, x, fmaf(ny, y, nz * z));
    Q8[(size_t)gid * 2]     = make_float4(x, nx, y, ny);
    Q8[(size_t)gid * 2 + 1] = make_float4(z, nz, sq, w);
    SD[gid] = enc_f(z);   // seed min with the plane-distance term z
}

// Kernel 2: grid = 56 pairs x 8 p-tiles = 448 blocks, 256 threads.
// Register tiling: each lane owns RPL=4 p's (slot r -> p = tile*256+r*64+lane)
// so each 32B q-record load is amortized over 4 pair-computations. This
// attacks R4-R6's real wall: a wave-uniform broadcast load writes 64x16B
// into the RF (~19 cyc of L1/L2 return per load) — at 1 p/lane that was
// 545k cyc/CU of pure data-return (= the observed 227us plateau).
// The 4 waves q-split 2048 into 512 each; q-stream kept on VMEM via the
// mbcnt divergent-zero (scalarizing to SMEM serializes on lgkmcnt drains).
// Body per pair: 3 v_pk_fma_f32 (c,s), sign packed into c's mantissa LSB,
// 10-deep med3 insertion (index-free). Epilogue: partials -> LDS
// [4][256][11] (stride 11: conflict-free), thread t exact-merges the 4
// chunk-lists for p_local=t, votes, sqrt, atomicMin.
__global__ void __launch_bounds__(TPB) k_pairs(const float4* __restrict__ Q8,
                                               unsigned int* __restrict__ SD) {
    __shared__ float TD[QCH][PCOV][KNN + 1];   // 44 KiB
    int bx   = blockIdx.x;
    int pair = bx >> 3;                  // / PTILES
    int tile = bx & (PTILES - 1);
    int b  = pair / 7;
    int oi = pair % 7;
    int o  = oi + (oi >= b ? 1 : 0);
    int tid  = threadIdx.x;
    int lane = tid & 63;
    int wave = tid >> 6;

    // per-slot constants from the RPL p-records
    float sqp;                           // only needed for final p (reloaded)
    f32x2 B1[RPL], B2[RPL], B3[RPL];
#pragma unroll
    for (int r = 0; r < RPL; r++) {
        int p = tile * PCOV + r * 64 + lane;
        const float4* Qp = Q8 + ((size_t)b * N_PTS + p) * 2;
        float4 u = Qp[0];                // (x, nx, y, ny)
        float4 v = Qp[1];                // (z, nz, sq, w)
        B1[r] = (f32x2){-2.0f * u.x, -u.x};
        B2[r] = (f32x2){-2.0f * u.z, -u.z};
        B3[r] = (f32x2){-2.0f * v.x, -v.x};
    }

    // divergent-looking zero: keeps the q-stream on the VMEM path
    int dz0 = (int)__builtin_amdgcn_mbcnt_lo(0u, 0u);
    const float4* Qo = Q8 + ((size_t)o * N_PTS + wave * QLEN + dz0) * 2;

    const float FMAXE = __uint_as_float(0x7F7FFFFEu);   // FLT_MAX, LSB clear
    float td[RPL][KNN];
#pragma unroll
    for (int r = 0; r < RPL; r++)
#pragma unroll
        for (int j = 0; j < KNN; j++) td[r][j] = FMAXE;

#pragma unroll 2
    for (int q = 0; q < QLEN; q++) {
        float4 a0 = Qo[2 * q];           // (x, nx, y, ny)
        float4 a1 = Qo[2 * q + 1];       // (z, nz, sq, w)
        f32x2 A1 = {a0.x, a0.y};
        f32x2 A2 = {a0.z, a0.w};
        f32x2 A3 = {a1.x, a1.y};
        f32x2 C0 = {a1.z, a1.w};
#pragma unroll
        for (int r = 0; r < RPL; r++) {
            f32x2 rr = __builtin_elementwise_fma(A1, B1[r],
                       __builtin_elementwise_fma(A2, B2[r],
                       __builtin_elementwise_fma(A3, B3[r], C0)));
            // rr.x = sq_q - 2 dot(xq,xp_r)   (d2 minus constant sq_p)
            // rr.y = dot(n_q, xq - xp_r)     (inside sign)
            unsigned int cu = (__float_as_uint(rr.x) & 0xFFFFFFFEu)
                            + (rr.y > 0.0f ? 1u : 0u);
            float cp = __uint_as_float(cu);
#pragma unroll
            for (int j = KNN - 1; j >= 1; --j)
                td[r][j] = __builtin_amdgcn_fmed3f(td[r][j - 1], td[r][j], cp);
            td[r][0] = fminf(td[r][0], cp);
        }
    }

    // dump all partial lists: chunk=wave, p_local = r*64+lane
#pragma unroll
    for (int r = 0; r < RPL; r++)
#pragma unroll
        for (int j = 0; j < KNN; j++)
            TD[wave][r * 64 + lane][j] = td[r][j];
    __syncthreads();

    // thread t finalizes p_local = t: merge the 4 chunk-lists from LDS
    {
        int p = tile * PCOV + tid;
        sqp = Q8[((size_t)b * N_PTS + p) * 2 + 1].z;   // L1-hot reload
        float fin[KNN];
#pragma unroll
        for (int j = 0; j < KNN; j++) fin[j] = FMAXE;
#pragma unroll
        for (int w2 = 0; w2 < QCH; w2++) {
#pragma unroll
            for (int j = 0; j < KNN; j++) {
                float cp = TD[w2][tid][j];
#pragma unroll
                for (int jj = KNN - 1; jj >= 1; --jj)
                    fin[jj] = __builtin_amdgcn_fmed3f(fin[jj - 1], fin[jj], cp);
                fin[0] = fminf(fin[0], cp);
            }
        }
        int cnt = 0;
#pragma unroll
        for (int j = 0; j < KNN; j++) cnt += (int)(__float_as_uint(fin[j]) & 1u);
        float d2 = __uint_as_float(__float_as_uint(fin[0]) & 0xFFFFFFFEu) + sqp;
        float d0 = sqrtf(fmaxf(d2, 0.0f));
        if (cnt > 8) d0 = -d0;           // sum(insides) > k*0.8 = 8  ->  >= 9
        atomicMin(&SD[b * N_PTS + p], enc_f(d0));
    }
}

// Kernel 3: decode and emit both outputs (signed_distance, then intersects
// as 0.0/1.0 floats).
__global__ void k_final(const unsigned int* __restrict__ SD,
                        float* __restrict__ out) {
    int gid = blockIdx.x * blockDim.x + threadIdx.x;
    if (gid >= N_OBJ * N_PTS) return;
    float sd = dec_f(SD[gid]);
    out[gid] = sd;
    out[N_OBJ * N_PTS + gid] = (sd < -TOLC) ? 1.0f : 0.0f;
}

extern "C" void kernel_launch(void* const* d_in, const int* in_sizes, int n_in,
                              void* d_out, int out_size, void* d_ws, size_t ws_size,
                              hipStream_t stream) {
    const float* pts     = (const float*)d_in[0];   // (8,2048,6)
    const float* T_est   = (const float*)d_in[1];   // (8,4,4)
    const float* T_plane = (const float*)d_in[2];   // (4,4)
    // d_in[3] is k == 10, hardcoded as KNN

    // workspace layout: Q8 (512KB interleaved records) | SD (64KB)
    float4*       Q8 = (float4*)d_ws;
    unsigned int* SD = (unsigned int*)(Q8 + (size_t)N_OBJ * N_PTS * 2);

    float* out = (float*)d_out;

    k_transform<<<(N_OBJ * N_PTS) / 256, 256, 0, stream>>>(pts, T_est, T_plane, Q8, SD);
    k_pairs<<<N_OBJ * (N_OBJ - 1) * PTILES, TPB, 0, stream>>>(Q8, SD);
    k_final<<<(N_OBJ * N_PTS) / 256, 256, 0, stream>>>(SD, out);
}